// Round 1
// 824.119 us; speedup vs baseline: 1.0414x; 1.0414x over previous
//
#include <hip/hip_runtime.h>
#include <cstdint>
#include <cstddef>

#define ROW 963  // 3 coords + 64 + 128 + 256 + 512 channels

__device__ __forceinline__ float bf2f(unsigned short u) {
    return __uint_as_float(((unsigned int)u) << 16);
}
__device__ __forceinline__ unsigned short f2bf(float v) {
    unsigned int u = __float_as_uint(v);
    // round-to-nearest-even
    u += 0x7FFFu + ((u >> 16) & 1u);
    return (unsigned short)(u >> 16);
}

// Fused NCHW fp32 -> NHWC bf16 for all 4 pyramid levels.
// v2: thread indexes the OUTPUT (NHWC) element, so the 2B bf16 writes are
// fully coalesced (128 B per wave). The fp32 reads become stride-SS gathers,
// but the per-wave line working set (64 lines) is L1-resident for f1/f2 and
// the whole level is L2-resident for f3/f4 (<= 1.5 MB/batch), so the read
// scatter is absorbed by cache instead of costing 64 write requests/instr.
// Level boundaries 200704/301056/351232 are multiples of 64 -> wave-uniform.
// grid.x = 1470 covers exactly 376320 = 1470*256 outputs per batch.
__global__ __launch_bounds__(256) void trans_all_k(
    const float* __restrict__ f1, const float* __restrict__ f2,
    const float* __restrict__ f3, const float* __restrict__ f4,
    unsigned short* __restrict__ o1, unsigned short* __restrict__ o2,
    unsigned short* __restrict__ o3, unsigned short* __restrict__ o4) {
    int r = blockIdx.x * 256 + threadIdx.x;
    int b = blockIdx.y;
    const float* src; unsigned short* dst; int SS, rr, lc;
    if (r < 200704)      { src = f1; dst = o1; SS = 3136; rr = r;          lc = 6; }
    else if (r < 301056) { src = f2; dst = o2; SS = 784;  rr = r - 200704; lc = 7; }
    else if (r < 351232) { src = f3; dst = o3; SS = 196;  rr = r - 301056; lc = 8; }
    else                 { src = f4; dst = o4; SS = 49;   rr = r - 351232; lc = 9; }
    int C  = 1 << lc;
    int c  = rr & (C - 1);   // channel (fast-varying -> coalesced writes)
    int sp = rr >> lc;       // spatial index i*S + j
    float v = src[(size_t)b * ((size_t)C * SS) + (size_t)c * SS + sp];
    dst[(size_t)b * ((size_t)SS * C) + rr] = f2bf(v);
}

// v2 projection kernel.
//  - grid-stride over points with ~2048 blocks (8192 waves = full occupancy)
//    instead of 200k one-shot workgroups: removes WG-dispatch overhead.
//  - all B batches handled inside the point loop: geometry + bilinear weights
//    computed once per point instead of once per (point,batch).
//  - no LDS, no barrier: thread t's 4 outputs are contiguous, so direct
//    per-lane stores are exactly as coalesced as the old staged copy.
// Thread t<240 owns channels [4t,4t+4); chunk boundaries 16/48/112.
__global__ __launch_bounds__(256) void proj_bf16_k(
    const float* __restrict__ coord,  // [N,3], batch-0 coords shared across b
    const unsigned short* __restrict__ t1, const unsigned short* __restrict__ t2,
    const unsigned short* __restrict__ t3, const unsigned short* __restrict__ t4,
    float* __restrict__ out, int N, int B) {
    int t = threadIdx.x;

    // per-thread static geometry (loop-invariant)
    const unsigned short* T; int S, C, cs;
    if (t < 16)       { T = t1; S = 56; C = 64;  cs = 0; }
    else if (t < 48)  { T = t2; S = 28; C = 128; cs = 16; }
    else if (t < 112) { T = t3; S = 14; C = 256; cs = 48; }
    else              { T = t4; S = 7;  C = 512; cs = 112; }
    int cc = (t - cs) * 4;  // channel within level, multiple of 4 -> 8B aligned
    float scale = (float)S * (1.0f / 224.0f);  // exact power-of-two mul
    float sm1 = (float)(S - 1);
    size_t lvl = (size_t)(S * S) * C;          // per-batch elements of my level
    bool active = (t < 240);

    for (int n = blockIdx.x; n < N; n += gridDim.x) {
        float X = coord[3 * n + 0];
        float Y = coord[3 * n + 1];
        float Z = coord[3 * n + 2];
        // exact same fp32 op sequence as the reference
        float h = fminf(fmaxf((250.0f * -Y) / (-Z) + 112.0f, 0.0f), 223.0f);
        float w = fminf(fmaxf((250.0f * X) / (-Z) + 112.0f, 0.0f), 223.0f);
        float x = fminf(fmaxf(h * scale, 0.0f), sm1);
        float y = fminf(fmaxf(w * scale, 0.0f), sm1);
        float x1f = floorf(x), x2f = ceilf(x);
        float y1f = floorf(y), y2f = ceilf(y);
        int x1 = (int)x1f, x2 = (int)x2f;
        int y1 = (int)y1f, y2 = (int)y2f;
        float dx1 = x - x1f, dx2 = x2f - x;
        float dy1 = y - y1f, dy2 = y2f - y;
        float w11 = dx2 * dy2, w21 = dx1 * dy2, w12 = dx2 * dy1, w22 = dx1 * dy1;
        // element offsets within one batch's level table (no deref for t>=240)
        int i11 = (x1 * S + y1) * C + cc;
        int i12 = (x1 * S + y2) * C + cc;
        int i21 = (x2 * S + y1) * C + cc;
        int i22 = (x2 * S + y2) * C + cc;

        for (int b = 0; b < B; ++b) {
            size_t orow = ((size_t)b * N + n) * ROW;
            if (active) {
                const unsigned short* base = T + (size_t)b * lvl;
                ushort4 q11 = *(const ushort4*)(base + i11);
                ushort4 q12 = *(const ushort4*)(base + i12);
                ushort4 q21 = *(const ushort4*)(base + i21);
                ushort4 q22 = *(const ushort4*)(base + i22);
                float v0 = w11 * bf2f(q11.x) + w21 * bf2f(q21.x) + w12 * bf2f(q12.x) + w22 * bf2f(q22.x);
                float v1 = w11 * bf2f(q11.y) + w21 * bf2f(q21.y) + w12 * bf2f(q12.y) + w22 * bf2f(q22.y);
                float v2 = w11 * bf2f(q11.z) + w21 * bf2f(q21.z) + w12 * bf2f(q12.z) + w22 * bf2f(q22.z);
                float v3 = w11 * bf2f(q11.w) + w21 * bf2f(q21.w) + w12 * bf2f(q12.w) + w22 * bf2f(q22.w);
                size_t o = orow + 3 + 4 * (size_t)t;
                out[o + 0] = v0; out[o + 1] = v1;
                out[o + 2] = v2; out[o + 3] = v3;
            } else if (t < 243) {
                out[orow + (t - 240)] = (t == 240) ? X : (t == 241) ? Y : Z;
            }
        }
    }
}

// Fallback: direct NCHW fp32 gather (only if d_ws is too small -- not expected).
__global__ __launch_bounds__(256) void proj_nchw_k(
    const float* __restrict__ coord,
    const float* __restrict__ f1, const float* __restrict__ f2,
    const float* __restrict__ f3, const float* __restrict__ f4,
    float* __restrict__ out, int N) {
    int n = blockIdx.x, b = blockIdx.y;
    float X = coord[3 * n + 0], Y = coord[3 * n + 1], Z = coord[3 * n + 2];
    float h = fminf(fmaxf((250.0f * -Y) / (-Z) + 112.0f, 0.0f), 223.0f);
    float w = fminf(fmaxf((250.0f * X) / (-Z) + 112.0f, 0.0f), 223.0f);
    size_t orow = ((size_t)b * N + n) * ROW;
    if (threadIdx.x < 3) out[orow + threadIdx.x] = coord[3 * n + threadIdx.x];
    for (int c = threadIdx.x; c < 960; c += 256) {
        const float* T; int S, C, cc;
        if (c < 64)       { T = f1; S = 56; C = 64;  cc = c; }
        else if (c < 192) { T = f2; S = 28; C = 128; cc = c - 64; }
        else if (c < 448) { T = f3; S = 14; C = 256; cc = c - 192; }
        else              { T = f4; S = 7;  C = 512; cc = c - 448; }
        float scale = (float)S * (1.0f / 224.0f);
        float sm1 = (float)(S - 1);
        float x = fminf(fmaxf(h * scale, 0.0f), sm1);
        float y = fminf(fmaxf(w * scale, 0.0f), sm1);
        float x1f = floorf(x), x2f = ceilf(x);
        float y1f = floorf(y), y2f = ceilf(y);
        int x1 = (int)x1f, x2 = (int)x2f, y1 = (int)y1f, y2 = (int)y2f;
        const float* base = T + ((size_t)b * C + cc) * (size_t)(S * S);
        float Q11 = base[x1 * S + y1], Q12 = base[x1 * S + y2];
        float Q21 = base[x2 * S + y1], Q22 = base[x2 * S + y2];
        float dx1 = x - x1f, dx2 = x2f - x, dy1 = y - y1f, dy2 = y2f - y;
        out[orow + 3 + c] = (dx2 * dy2) * Q11 + (dx1 * dy2) * Q21 +
                            (dx2 * dy1) * Q12 + (dx1 * dy1) * Q22;
    }
}

extern "C" void kernel_launch(void* const* d_in, const int* in_sizes, int n_in,
                              void* d_out, int out_size, void* d_ws, size_t ws_size,
                              hipStream_t stream) {
    const float* inputs = (const float*)d_in[0];  // [B,N,3]; batch 0 = coords
    const float* f1 = (const float*)d_in[1];      // [B,64,56,56]
    const float* f2 = (const float*)d_in[2];      // [B,128,28,28]
    const float* f3 = (const float*)d_in[3];      // [B,256,14,14]
    const float* f4 = (const float*)d_in[4];      // [B,512,7,7]
    float* out = (float*)d_out;

    int B = in_sizes[1] / (64 * 56 * 56);
    int N = in_sizes[0] / (B * 3);

    size_t n1 = (size_t)B * 200704;  // per-level bf16 element counts
    size_t n2 = (size_t)B * 100352;
    size_t n3 = (size_t)B * 50176;
    size_t n4 = (size_t)B * 25088;
    size_t need = (n1 + n2 + n3 + n4) * sizeof(unsigned short);

    dim3 blk(256);
    if (ws_size >= need) {
        unsigned short* o1 = (unsigned short*)d_ws;
        unsigned short* o2 = o1 + n1;
        unsigned short* o3 = o2 + n2;
        unsigned short* o4 = o3 + n3;
        trans_all_k<<<dim3(376320 / 256, B), blk, 0, stream>>>(
            f1, f2, f3, f4, o1, o2, o3, o4);
        // 2048 blocks x 4 waves = 8192 waves = 256 CU x 32 wave slots.
        int nblk = N < 2048 ? N : 2048;
        proj_bf16_k<<<dim3(nblk), blk, 0, stream>>>(inputs, o1, o2, o3, o4, out, N, B);
    } else {
        proj_nchw_k<<<dim3(N, B), blk, 0, stream>>>(inputs, f1, f2, f3, f4, out, N);
    }
}